// Round 2
// baseline (190.151 us; speedup 1.0000x reference)
//
#include <hip/hip_runtime.h>

#define NB 64
#define NC 206
#define N (NB * NC)   // 13184

// Workspace layout
struct Ws {
    float pw[N];          // positive weights (0 where not positive)
    float nw[N];          // negative weights (0 where not negative)
    double acc;           // global accumulator (8-aligned)
    unsigned int npos;
    unsigned int nneg;
};

__global__ __launch_bounds__(256) void prep_kernel(
    const float* __restrict__ preds,
    const float* __restrict__ sw,
    const int* __restrict__ labels,
    Ws* __restrict__ ws)
{
    int idx = blockIdx.x * blockDim.x + threadIdx.x;
    if (idx < N) {
        int b = idx / NC;
        float wt = sw[b];
        int l = labels[idx];
        ws->pw[idx] = (l == 1) ? wt : 0.0f;
        ws->nw[idx] = (l == 0) ? wt : 0.0f;
        // compiler coalesces these into one per-wave atomic each
        if (l == 1) atomicAdd(&ws->npos, 1u);
        else        atomicAdd(&ws->nneg, 1u);
    }
}

__global__ __launch_bounds__(256) void pairs_kernel(
    const float* __restrict__ preds,
    Ws* __restrict__ ws,
    int jchunk)
{
    const int i = blockIdx.x * 256 + threadIdx.x;
    float pi = 0.0f, pwi = 0.0f;
    if (i < N) {
        pi  = preds[i];
        pwi = ws->pw[i];
    }

    const int j0 = blockIdx.y * jchunk;
    const int j1 = min(j0 + jchunk, N);

    float acc = 0.0f;
    // skip entire loop only if EVERY lane in the wave has zero pos-weight
    if (__any(pwi != 0.0f)) {
        for (int j = j0; j < j1; ++j) {
            float nwj = ws->nw[j];          // uniform scalar load
            if (nwj == 0.0f) continue;      // uniform branch: free skip of neg-j
            float pj = preds[j];            // uniform scalar load
            float x  = pj - pi;             // = -(pi - pj) * margin, margin=1
            // stable softplus(x) = max(x,0) + log(1 + exp(-|x|))
            float sp = fmaxf(x, 0.0f) + __logf(1.0f + __expf(-fabsf(x)));
            acc = fmaf(sp, nwj, acc);
        }
    }
    acc *= pwi;   // zero for non-positive i

    // wave reduce (64 lanes)
    #pragma unroll
    for (int off = 32; off > 0; off >>= 1)
        acc += __shfl_down(acc, off, 64);

    __shared__ float wsum[4];
    int lane = threadIdx.x & 63;
    int wid  = threadIdx.x >> 6;
    if (lane == 0) wsum[wid] = acc;
    __syncthreads();
    if (threadIdx.x == 0) {
        float blocksum = wsum[0] + wsum[1] + wsum[2] + wsum[3];
        atomicAdd(&ws->acc, (double)blocksum);
    }
}

__global__ void finalize_kernel(const Ws* __restrict__ ws, float* __restrict__ out)
{
    double denom = (double)ws->npos * (double)ws->nneg;
    out[0] = (float)(ws->acc / denom);
}

extern "C" void kernel_launch(void* const* d_in, const int* in_sizes, int n_in,
                              void* d_out, int out_size, void* d_ws, size_t ws_size,
                              hipStream_t stream)
{
    const float* preds  = (const float*)d_in[0];
    const float* sw     = (const float*)d_in[1];
    const int*   labels = (const int*)d_in[2];
    float* out = (float*)d_out;
    Ws* ws = (Ws*)d_ws;

    // zero acc + counts (tail of Ws). pw/nw fully overwritten by prep.
    (void)hipMemsetAsync((char*)d_ws + offsetof(Ws, acc), 0,
                         sizeof(double) + 2 * sizeof(unsigned int), stream);

    const int iblocks = (N + 255) / 256;        // 52
    prep_kernel<<<iblocks, 256, 0, stream>>>(preds, sw, labels, ws);

    const int jsplits = 40;
    const int jchunk  = (N + jsplits - 1) / jsplits;  // 330
    dim3 grid(iblocks, jsplits);
    pairs_kernel<<<grid, 256, 0, stream>>>(preds, ws, jchunk);

    finalize_kernel<<<1, 1, 0, stream>>>(ws, out);
}

// Round 3
// 69.345 us; speedup vs baseline: 2.7421x; 2.7421x over previous
//
#include <hip/hip_runtime.h>

#define NB 64
#define NC 206
#define N (NB * NC)   // 13184

// Workspace layout: one float2 array; positives compact from the front,
// negatives compact from the back (npos + nneg == N always).
struct Ws {
    float2 slots[N];      // {pred, weight}
    double acc;           // global accumulator
    unsigned int npos;
    unsigned int nneg;
};

__global__ __launch_bounds__(256) void prep_kernel(
    const float* __restrict__ preds,
    const float* __restrict__ sw,
    const int* __restrict__ labels,
    Ws* __restrict__ ws)
{
    const int idx = blockIdx.x * 256 + threadIdx.x;
    const bool inb = (idx < N);
    float p = 0.0f, w = 0.0f;
    int l = -1;
    if (inb) {
        p = preds[idx];
        w = sw[idx / NC];
        l = labels[idx];
    }
    const int lane = threadIdx.x & 63;
    const bool isPos = inb && (l == 1);
    const bool isNeg = inb && (l == 0);

    // wave-aggregated slot allocation: ONE atomic per wave per list
    const unsigned long long balP = __ballot(isPos);
    const unsigned long long balN = __ballot(isNeg);
    const unsigned int cntP = __popcll(balP);
    const unsigned int cntN = __popcll(balN);
    unsigned int baseP = 0, baseN = 0;
    if (lane == 0) {
        if (cntP) baseP = atomicAdd(&ws->npos, cntP);
        if (cntN) baseN = atomicAdd(&ws->nneg, cntN);
    }
    baseP = __shfl(baseP, 0, 64);
    baseN = __shfl(baseN, 0, 64);
    const unsigned long long lanemask = (1ull << lane) - 1ull;  // exclusive prefix
    const unsigned int preP = __popcll(balP & lanemask);
    const unsigned int preN = __popcll(balN & lanemask);

    if (isPos) ws->slots[baseP + preP]            = make_float2(p, w);
    if (isNeg) ws->slots[N - 1 - (baseN + preN)]  = make_float2(p, w);
}

__global__ __launch_bounds__(256) void pairs_kernel(
    const float2* __restrict__ slots,
    const unsigned int* __restrict__ counts,   // [npos, nneg]
    double* __restrict__ accp)
{
    const int npos = (int)counts[0];
    const int nneg = (int)counts[1];

    const int i = blockIdx.x * 256 + threadIdx.x;
    float pi = 0.0f, pwi = 0.0f;
    if (i < npos) {
        float2 s = slots[i];
        pi  = s.x;
        pwi = s.y;
    }

    float acc = 0.0f;
    // uniform branch: blocks fully past npos skip the loop entirely
    if ((int)(blockIdx.x * 256) < npos) {
        const int negStart = N - nneg;
        const int per = (nneg + gridDim.y - 1) / gridDim.y;
        const int j0 = negStart + blockIdx.y * per;
        const int j1 = min(j0 + per, N);
        #pragma unroll 4
        for (int j = j0; j < j1; ++j) {
            float2 s = slots[j];            // block-uniform -> s_load_dwordx2
            float x  = s.x - pi;            // = -(pi - pn) * margin, margin=1
            // stable softplus(x) = max(x,0) + log(1 + exp(-|x|))
            float sp = fmaxf(x, 0.0f) + __logf(1.0f + __expf(-fabsf(x)));
            acc = fmaf(sp, s.y, acc);
        }
        acc *= pwi;   // per-pos weight
    }

    // wave reduce (64 lanes)
    #pragma unroll
    for (int off = 32; off > 0; off >>= 1)
        acc += __shfl_down(acc, off, 64);

    __shared__ float wsum[4];
    const int lane = threadIdx.x & 63;
    const int wid  = threadIdx.x >> 6;
    if (lane == 0) wsum[wid] = acc;
    __syncthreads();
    if (threadIdx.x == 0) {
        float blocksum = wsum[0] + wsum[1] + wsum[2] + wsum[3];
        atomicAdd(accp, (double)blocksum);
    }
}

__global__ void finalize_kernel(const Ws* __restrict__ ws, float* __restrict__ out)
{
    double denom = (double)ws->npos * (double)ws->nneg;
    out[0] = (float)(ws->acc / denom);
}

extern "C" void kernel_launch(void* const* d_in, const int* in_sizes, int n_in,
                              void* d_out, int out_size, void* d_ws, size_t ws_size,
                              hipStream_t stream)
{
    const float* preds  = (const float*)d_in[0];
    const float* sw     = (const float*)d_in[1];
    const int*   labels = (const int*)d_in[2];
    float* out = (float*)d_out;
    Ws* ws = (Ws*)d_ws;

    // zero acc + counts (tail of Ws). slots fully overwritten by prep.
    (void)hipMemsetAsync((char*)d_ws + offsetof(Ws, acc), 0,
                         sizeof(double) + 2 * sizeof(unsigned int), stream);

    const int iblocks = (N + 255) / 256;        // 52
    prep_kernel<<<iblocks, 256, 0, stream>>>(preds, sw, labels, ws);

    dim3 grid(iblocks, 32);
    pairs_kernel<<<grid, 256, 0, stream>>>(
        (const float2*)ws->slots, &ws->npos, &ws->acc);

    finalize_kernel<<<1, 1, 0, stream>>>(ws, out);
}

// Round 4
// 29.472 us; speedup vs baseline: 6.4519x; 2.3529x over previous
//
#include <hip/hip_runtime.h>

#define NB 64
#define NC 206
#define N (NB * NC)     // 13184
#define IPT 4           // positives per thread
#define GXMAX 13        // ceil(N / (256*IPT))
#define GY 96           // j-splits
#define NBLK (GXMAX * GY)
#define MAXCHUNK 140    // >= ceil(N/GY) = 138
#define LN2F 0.69314718056f

// Workspace: compacted transformed slots, counters, per-block partials.
// front of slots: positives {exp(-p), w}; back: negatives {exp(p), w*ln2}
struct Ws {
    float2 slots[N];
    unsigned int npos;
    unsigned int nneg;
    double partials[NBLK];   // 8-aligned (105472+8)
};

__global__ __launch_bounds__(256) void prep_kernel(
    const float* __restrict__ preds,
    const float* __restrict__ sw,
    const int* __restrict__ labels,
    Ws* __restrict__ ws)
{
    const int idx = blockIdx.x * 256 + threadIdx.x;
    const bool inb = (idx < N);
    float p = 0.0f, w = 0.0f;
    int l = -1;
    if (inb) {
        p = preds[idx];
        w = sw[idx / NC];
        l = labels[idx];
    }
    const int lane = threadIdx.x & 63;
    const bool isPos = inb && (l == 1);
    const bool isNeg = inb && (l == 0);

    // wave-aggregated slot allocation: one atomic per wave per list
    const unsigned long long balP = __ballot(isPos);
    const unsigned long long balN = __ballot(isNeg);
    unsigned int baseP = 0, baseN = 0;
    if (lane == 0) {
        unsigned int cP = __popcll(balP), cN = __popcll(balN);
        if (cP) baseP = atomicAdd(&ws->npos, cP);
        if (cN) baseN = atomicAdd(&ws->nneg, cN);
    }
    baseP = __shfl(baseP, 0, 64);
    baseN = __shfl(baseN, 0, 64);
    const unsigned long long lanemask = (1ull << lane) - 1ull;
    const unsigned int preP = __popcll(balP & lanemask);
    const unsigned int preN = __popcll(balN & lanemask);

    if (isPos) ws->slots[baseP + preP]           = make_float2(__expf(-p), w);
    if (isNeg) ws->slots[N - 1 - (baseN + preN)] = make_float2(__expf(p), w * LN2F);
}

__global__ __launch_bounds__(256) void pairs_kernel(
    const Ws* __restrict__ ws,
    double* __restrict__ partials)
{
    const int bid  = blockIdx.y * gridDim.x + blockIdx.x;
    const int npos = (int)ws->npos;
    const int nneg = (int)ws->nneg;
    const int i0   = blockIdx.x * (256 * IPT);

    if (i0 >= npos) {                 // block-uniform early-out
        if (threadIdx.x == 0) partials[bid] = 0.0;
        return;
    }

    // stage this block's negative chunk into LDS
    __shared__ float2 stage[MAXCHUNK];
    const int per = (nneg + GY - 1) / GY;
    const int j0  = blockIdx.y * per;
    const int jn  = min(per, nneg - j0);       // may be <= 0
    const float2* negBase = ws->slots + (N - nneg);
    for (int t = threadIdx.x; t < jn; t += 256)
        stage[t] = negBase[j0 + t];
    __syncthreads();

    float F[IPT], PW[IPT], acc[IPT];
    #pragma unroll
    for (int k = 0; k < IPT; ++k) {
        int i = i0 + k * 256 + threadIdx.x;
        if (i < npos) { float2 s = ws->slots[i]; F[k] = s.x; PW[k] = s.y; }
        else          { F[k] = 0.0f; PW[k] = 0.0f; }   // t=1 -> log=0 contribution
        acc[k] = 0.0f;
    }

    // core loop: 3 VALU ops per pair (fma, v_log_f32, fma)
    #pragma unroll 2
    for (int j = 0; j < jn; ++j) {
        float2 s = stage[j];           // broadcast ds_read, conflict-free
        #pragma unroll
        for (int k = 0; k < IPT; ++k) {
            float t = fmaf(s.x, F[k], 1.0f);         // 1 + e^{pn}·e^{-pp}
            acc[k] = fmaf(__log2f(t), s.y, acc[k]);  // += log2(t)·(w·ln2)
        }
    }

    float a = 0.0f;
    #pragma unroll
    for (int k = 0; k < IPT; ++k) a = fmaf(acc[k], PW[k], a);

    #pragma unroll
    for (int off = 32; off > 0; off >>= 1)
        a += __shfl_down(a, off, 64);

    __shared__ float wsum[4];
    const int lane = threadIdx.x & 63;
    const int wid  = threadIdx.x >> 6;
    if (lane == 0) wsum[wid] = a;
    __syncthreads();
    if (threadIdx.x == 0)
        partials[bid] = (double)(wsum[0] + wsum[1] + wsum[2] + wsum[3]);
}

__global__ __launch_bounds__(256) void reduce_kernel(
    const Ws* __restrict__ ws,
    float* __restrict__ out)
{
    double s = 0.0;
    for (int t = threadIdx.x; t < NBLK; t += 256)
        s += ws->partials[t];

    #pragma unroll
    for (int off = 32; off > 0; off >>= 1)
        s += __shfl_down(s, off, 64);

    __shared__ double ds[4];
    const int lane = threadIdx.x & 63;
    const int wid  = threadIdx.x >> 6;
    if (lane == 0) ds[wid] = s;
    __syncthreads();
    if (threadIdx.x == 0) {
        double total = ds[0] + ds[1] + ds[2] + ds[3];
        double denom = (double)ws->npos * (double)ws->nneg;
        out[0] = (float)(total / denom);
    }
}

extern "C" void kernel_launch(void* const* d_in, const int* in_sizes, int n_in,
                              void* d_out, int out_size, void* d_ws, size_t ws_size,
                              hipStream_t stream)
{
    const float* preds  = (const float*)d_in[0];
    const float* sw     = (const float*)d_in[1];
    const int*   labels = (const int*)d_in[2];
    float* out = (float*)d_out;
    Ws* ws = (Ws*)d_ws;

    // zero the two compaction counters only
    (void)hipMemsetAsync((char*)d_ws + offsetof(Ws, npos), 0,
                         2 * sizeof(unsigned int), stream);

    const int iblocks = (N + 255) / 256;   // 52
    prep_kernel<<<iblocks, 256, 0, stream>>>(preds, sw, labels, ws);

    dim3 grid(GXMAX, GY);
    pairs_kernel<<<grid, 256, 0, stream>>>(ws, ws->partials);

    reduce_kernel<<<1, 256, 0, stream>>>(ws, out);
}